// Round 19
// baseline (28.289 us; speedup 1.0000x reference)
//
#include <hip/hip_runtime.h>
#include <math.h>

// Batched 8-qubit state-vector sim. fp32 in / fp32 out.
// Base: R18 (PASSED, 26.0us; fused RZ diagonal via complex-mult phases +
// cnot-cascade bpermute + closed-form RY init + fused post-cycle 4x4 gates).
// This round: DS-pipe offload (retry of R13 now that DS dominates):
//   mask 8  -> DPP row_ror:8          (validated R13)
//   mask 16 -> permlane16_swap+cndmask (validated R13)
//   mask 24 -> compose 8 then 16 (VALU), mask 10 -> compose 8 then 2 (DPP)
//   masks 4,6 remain ds_swizzle; cascade remains ds_bpermute.
// Layout: one element per 32-lane group; a = L*8 + r; wire w -> bit 7-w;
// bit<3 = reg bit (mask 1<<bit), bit>=3 = lane bit (mask 1<<(bit-3)).

constexpr int NREG = 8;

typedef float v2f __attribute__((ext_vector_type(2)));
typedef unsigned int uv2 __attribute__((ext_vector_type(2)));

__device__ __forceinline__ v2f vfma(v2f a, v2f b, v2f c) {
  return __builtin_elementwise_fma(a, b, c);
}
__device__ __forceinline__ v2f splat(float x) { return (v2f){x, x}; }

template<int MASK>
__device__ __forceinline__ float lxor(float x) {
  if constexpr (MASK == 24) {
    return lxor<16>(lxor<8>(x));
  } else if constexpr (MASK == 10) {
    return lxor<2>(lxor<8>(x));
  } else {
    int xi = __float_as_int(x);
    int r;
    if constexpr (MASK == 1) {
      r = __builtin_amdgcn_mov_dpp(xi, 0xB1, 0xF, 0xF, true);   // quad_perm [1,0,3,2]
    } else if constexpr (MASK == 2) {
      r = __builtin_amdgcn_mov_dpp(xi, 0x4E, 0xF, 0xF, true);   // quad_perm [2,3,0,1]
    } else if constexpr (MASK == 8) {
      r = __builtin_amdgcn_mov_dpp(xi, 0x128, 0xF, 0xF, true);  // row_ror:8 == lane^8
    }
#if defined(__has_builtin)
#if __has_builtin(__builtin_amdgcn_permlane16_swap)
    else if constexpr (MASK == 16) {
      uv2 p = __builtin_amdgcn_permlane16_swap((unsigned)xi, (unsigned)xi, false, false);
      r = (int)(((threadIdx.x >> 4) & 1) ? p.x : p.y);
    }
#endif
#endif
    else {
      r = __builtin_amdgcn_ds_swizzle(xi, (MASK << 10) | 0x1F); // xor within 32 lanes
    }
    return __int_as_float(r);
  }
}

template<int MASK>
__device__ __forceinline__ v2f lxor2(v2f v) {
  v2f r;
  r.x = lxor<MASK>(v.x);
  r.y = lxor<MASK>(v.y);
  return r;
}

struct State {
  v2f a[NREG];  // a[r] = (re, im)
};

// ---------------- cycle-layer gates (validated R12/R17) ----------------

template<int P>
__device__ __forceinline__ void ry_gate(State& st, float c, float s, int L) {
  if constexpr (P <= 2) {
    constexpr int m = 1 << P;
    #pragma unroll
    for (int r0 = 0; r0 < NREG; ++r0) {
      if (r0 & m) continue;
      const int r1 = r0 | m;
      v2f a0 = st.a[r0], a1 = st.a[r1];
      st.a[r0] = vfma(splat(-s), a1, splat(c) * a0);
      st.a[r1] = vfma(splat( s), a0, splat(c) * a1);
    }
  } else {
    constexpr int m = 1 << (P - 3);
    float ss = ((L >> (P - 3)) & 1) ? s : -s;
    #pragma unroll
    for (int r = 0; r < NREG; ++r) {
      v2f b = lxor2<m>(st.a[r]);
      st.a[r] = vfma(splat(ss), b, splat(c) * st.a[r]);
    }
  }
}

template<int PC, int PT>
__device__ __forceinline__ void cnot_gate(State& st, int L) {
  if constexpr (PT <= 2) {
    constexpr int mt = 1 << PT;
    if constexpr (PC <= 2) {
      constexpr int mc = 1 << PC;
      #pragma unroll
      for (int r0 = 0; r0 < NREG; ++r0) {
        if (!(r0 & mc) || (r0 & mt)) continue;
        const int r1 = r0 | mt;
        v2f t = st.a[r0]; st.a[r0] = st.a[r1]; st.a[r1] = t;
      }
    } else {
      bool cb = (L >> (PC - 3)) & 1;
      #pragma unroll
      for (int r0 = 0; r0 < NREG; ++r0) {
        if (r0 & mt) continue;
        const int r1 = r0 | mt;
        v2f a0 = st.a[r0], a1 = st.a[r1];
        st.a[r0] = cb ? a1 : a0;
        st.a[r1] = cb ? a0 : a1;
      }
    }
  } else {
    constexpr int mt = 1 << (PT - 3);
    if constexpr (PC <= 2) {
      constexpr int mc = 1 << PC;
      #pragma unroll
      for (int r = 0; r < NREG; ++r) {
        if (!(r & mc)) continue;
        st.a[r] = lxor2<mt>(st.a[r]);
      }
    } else {
      bool cb = (L >> (PC - 3)) & 1;
      #pragma unroll
      for (int r = 0; r < NREG; ++r) {
        v2f b = lxor2<mt>(st.a[r]);
        st.a[r] = cb ? b : st.a[r];
      }
    }
  }
}

// ring CNOTs (0,1),(1,2),(2,3),(3,4) composed into one lane pull:
// src lane for lane y is y ^ ((y>>1)&15); bp_addr precomputed (bytes).
__device__ __forceinline__ void cnot_cascade(State& st, int bp_addr) {
  #pragma unroll
  for (int r = 0; r < NREG; ++r) {
    int xr = __builtin_amdgcn_ds_bpermute(bp_addr, __float_as_int(st.a[r].x));
    int xi = __builtin_amdgcn_ds_bpermute(bp_addr, __float_as_int(st.a[r].y));
    st.a[r].x = __int_as_float(xr);
    st.a[r].y = __int_as_float(xi);
  }
}

// t += (ur + i*ui) * v
__device__ __forceinline__ v2f cmac(v2f t, v2f u, v2f v) {
  t = vfma(splat(u.x), v, t);
  t = vfma((v2f){-u.y, u.y}, v.yx, t);
  return t;
}

__device__ __forceinline__ v2f ld2(const float* p) {
  return (v2f){p[0], p[1]};
}

// ---------------- fused 4x4 gate application (validated R15/R16) ------------

template<int MH, int ML>
__device__ __forceinline__ void apply_G_ll(State& st, const float* g, int L) {
  const int bh = (L & MH) ? 1 : 0;
  const int bl = (L & ML) ? 1 : 0;
  const int row = (bh << 1) | bl;
  const float* gr = g + row * 8;
  const v2f cS = ld2(gr + 2 * row);
  const v2f cL = ld2(gr + 2 * (row ^ 1));
  const v2f cH = ld2(gr + 2 * (row ^ 2));
  const v2f cB = ld2(gr + 2 * (row ^ 3));
  #pragma unroll
  for (int r = 0; r < NREG; ++r) {
    v2f v = st.a[r];
    v2f pl = lxor2<ML>(v);
    v2f ph = lxor2<MH>(v);
    v2f pb = lxor2<MH | ML>(v);
    v2f t = (v2f){0.f, 0.f};
    t = cmac(t, cS, v);
    t = cmac(t, cL, pl);
    t = cmac(t, cH, ph);
    t = cmac(t, cB, pb);
    st.a[r] = t;
  }
}

template<int MHR, int MLR>
__device__ __forceinline__ void apply_G_rr(State& st, const float* g) {
  #pragma unroll
  for (int base = 0; base < NREG; ++base) {
    if (base & (MHR | MLR)) continue;
    v2f in0 = st.a[base];
    v2f in1 = st.a[base | MLR];
    v2f in2 = st.a[base | MHR];
    v2f in3 = st.a[base | MHR | MLR];
    #pragma unroll
    for (int i = 0; i < 4; ++i) {
      v2f t = (v2f){0.f, 0.f};
      t = cmac(t, ld2(g + i * 8 + 0), in0);
      t = cmac(t, ld2(g + i * 8 + 2), in1);
      t = cmac(t, ld2(g + i * 8 + 4), in2);
      t = cmac(t, ld2(g + i * 8 + 6), in3);
      if (i == 0) st.a[base] = t;
      else if (i == 1) st.a[base | MLR] = t;
      else if (i == 2) st.a[base | MHR] = t;
      else st.a[base | MHR | MLR] = t;
    }
  }
}

template<int MREG, int ML>
__device__ __forceinline__ void apply_G_mx(State& st, const float* g, int L) {
  const int bl = (L & ML) ? 1 : 0;
  const int r0w = bl;
  const int r1w = 2 + bl;
  const float* g0 = g + r0w * 8;
  const float* g1 = g + r1w * 8;
  const v2f c0S = ld2(g0 + 2 * r0w),       c0L = ld2(g0 + 2 * (r0w ^ 1));
  const v2f c0H = ld2(g0 + 2 * (r0w ^ 2)), c0B = ld2(g0 + 2 * (r0w ^ 3));
  const v2f c1S = ld2(g1 + 2 * r1w),       c1L = ld2(g1 + 2 * (r1w ^ 1));
  const v2f c1H = ld2(g1 + 2 * (r1w ^ 2)), c1B = ld2(g1 + 2 * (r1w ^ 3));
  v2f x[NREG];
  #pragma unroll
  for (int r = 0; r < NREG; ++r) x[r] = lxor2<ML>(st.a[r]);
  v2f o[NREG];
  #pragma unroll
  for (int r = 0; r < NREG; ++r) {
    v2f t = (v2f){0.f, 0.f};
    if (r & MREG) {
      t = cmac(t, c1S, st.a[r]);
      t = cmac(t, c1L, x[r]);
      t = cmac(t, c1H, st.a[r ^ MREG]);
      t = cmac(t, c1B, x[r ^ MREG]);
    } else {
      t = cmac(t, c0S, st.a[r]);
      t = cmac(t, c0L, x[r]);
      t = cmac(t, c0H, st.a[r ^ MREG]);
      t = cmac(t, c0B, x[r ^ MREG]);
    }
    o[r] = t;
  }
  #pragma unroll
  for (int r = 0; r < NREG; ++r) st.a[r] = o[r];
}

// ---------------- gate-build helpers (4-dim basis column) ----------------

__device__ __forceinline__ void b_phase(float* cr, float* ci, int i, float pc, float ps) {
  float r = cr[i] * pc - ci[i] * ps;
  float m = cr[i] * ps + ci[i] * pc;
  cr[i] = r; ci[i] = m;
}
__device__ __forceinline__ void b_rz_hi(float* cr, float* ci, float t) {
  float s, c; sincosf(0.5f * t, &s, &c);
  b_phase(cr, ci, 0, c, -s); b_phase(cr, ci, 1, c, -s);
  b_phase(cr, ci, 2, c,  s); b_phase(cr, ci, 3, c,  s);
}
__device__ __forceinline__ void b_rz_lo(float* cr, float* ci, float t) {
  float s, c; sincosf(0.5f * t, &s, &c);
  b_phase(cr, ci, 0, c, -s); b_phase(cr, ci, 2, c, -s);
  b_phase(cr, ci, 1, c,  s); b_phase(cr, ci, 3, c,  s);
}
__device__ __forceinline__ void b_ry_hi(float* cr, float* ci, float t) {
  float s, c; sincosf(0.5f * t, &s, &c);
  #pragma unroll
  for (int lo = 0; lo < 2; ++lo) {
    int i0 = lo, i1 = 2 + lo;
    float n0r = c * cr[i0] - s * cr[i1], n0i = c * ci[i0] - s * ci[i1];
    float n1r = s * cr[i0] + c * cr[i1], n1i = s * ci[i0] + c * ci[i1];
    cr[i0] = n0r; ci[i0] = n0i; cr[i1] = n1r; ci[i1] = n1i;
  }
}
__device__ __forceinline__ void b_swap(float* cr, float* ci, int i, int j) {
  float t;
  t = cr[i]; cr[i] = cr[j]; cr[j] = t;
  t = ci[i]; ci[i] = ci[j]; ci[j] = t;
}
__device__ __forceinline__ void b_u2(float* cr, float* ci, int i0, int i1,
    float u00r, float u00i, float u01r, float u01i,
    float u10r, float u10i, float u11r, float u11i) {
  float v0r = cr[i0], v0i = ci[i0], v1r = cr[i1], v1i = ci[i1];
  cr[i0] = u00r*v0r - u00i*v0i + u01r*v1r - u01i*v1i;
  ci[i0] = u00r*v0i + u00i*v0r + u01r*v1i + u01i*v1r;
  cr[i1] = u10r*v0r - u10i*v0i + u11r*v1r - u11i*v1i;
  ci[i1] = u10r*v0i + u10i*v0r + u11r*v1i + u11i*v1r;
}
__device__ __forceinline__ void b_u3(float* cr, float* ci, bool on_hi,
                                     float t, float p, float l) {
  float st_, ct, sp, cp, sl, cl;
  sincosf(0.5f * t, &st_, &ct);
  sincosf(p, &sp, &cp);
  sincosf(l, &sl, &cl);
  float u00r = ct,        u00i = 0.f;
  float u01r = -cl * st_, u01i = -sl * st_;
  float u10r = cp * st_,  u10i = sp * st_;
  float eplr = cp * cl - sp * sl, epli = sp * cl + cp * sl;
  float u11r = eplr * ct, u11i = epli * ct;
  if (on_hi) {
    b_u2(cr, ci, 0, 2, u00r,u00i,u01r,u01i,u10r,u10i,u11r,u11i);
    b_u2(cr, ci, 1, 3, u00r,u00i,u01r,u01i,u10r,u10i,u11r,u11i);
  } else {
    b_u2(cr, ci, 0, 1, u00r,u00i,u01r,u01i,u10r,u10i,u11r,u11i);
    b_u2(cr, ci, 2, 3, u00r,u00i,u01r,u01i,u10r,u10i,u11r,u11i);
  }
}

// ---------------- kernel 1: build 7 fused 4x4 gates into d_ws --------------

__global__ __launch_bounds__(64, 1) void build_gates_kernel(
    const float* __restrict__ rz_a, const float* __restrict__ ry_a,
    const float* __restrict__ u3_p, float* __restrict__ ws) {
  const int tid = threadIdx.x;
  if (tid >= 28) return;
  const int t = tid >> 2;
  const int j = tid & 3;
  float cr[4] = {0.f, 0.f, 0.f, 0.f};
  float ci[4] = {0.f, 0.f, 0.f, 0.f};
  cr[j] = 1.f;
  b_rz_hi(cr, ci, rz_a[3 * t]);
  b_swap(cr, ci, 2, 3);                 // cnot(hi,lo)
  b_rz_lo(cr, ci, rz_a[3 * t + 1]);
  b_ry_hi(cr, ci, ry_a[2 * t]);
  b_swap(cr, ci, 1, 3);                 // cnot(lo,hi)
  b_ry_hi(cr, ci, ry_a[2 * t + 1]);
  b_swap(cr, ci, 2, 3);                 // cnot(hi,lo)
  b_rz_lo(cr, ci, rz_a[3 * t + 2]);
  if (t < 4)       b_u3(cr, ci, true,  u3_p[3*t], u3_p[3*t+1], u3_p[3*t+2]);
  else if (t == 5) b_u3(cr, ci, true,  u3_p[15],  u3_p[16],    u3_p[17]);
  else if (t == 6) b_u3(cr, ci, false, u3_p[12],  u3_p[13],    u3_p[14]);
  #pragma unroll
  for (int i = 0; i < 4; ++i) {
    ws[t * 32 + i * 8 + j * 2]     = cr[i];
    ws[t * 32 + i * 8 + j * 2 + 1] = ci[i];
  }
}

// ---------------- kernel 2: main ----------------

__global__ __launch_bounds__(256, 4) void qcnn_kernel(
    const float* __restrict__ theta, const float* __restrict__ phi,
    const float* __restrict__ ws,
    const float* __restrict__ w1, const float* __restrict__ b1,
    const float* __restrict__ w2, const float* __restrict__ b2,
    float* __restrict__ out, int B) {
  __shared__ float sG[7 * 32] __attribute__((aligned(16)));
  __shared__ float s_w1[20];
  __shared__ float s_b1[10];
  __shared__ float s_w2[10];
  __shared__ float s_b2[1];

  const int tid = threadIdx.x;
  if (tid < 224) sG[tid] = ws[tid];
  if (tid < 20) s_w1[tid] = w1[tid];
  else if (tid >= 32 && tid < 42) s_b1[tid - 32] = b1[tid - 32];
  else if (tid >= 64 && tid < 74) s_w2[tid - 64] = w2[tid - 64];
  else if (tid == 96) s_b2[0] = b2[0];
  __syncthreads();

  const int L = tid & 31;
  const int wv = tid & 63;
  // src lane for ring CNOT cascade (0,1)(1,2)(2,3)(3,4): y ^ ((y>>1)&15)
  const int bp_addr = ((wv & 32) | ((wv & 31) ^ (((wv & 31) >> 1) & 15))) << 2;
  const int g = (blockIdx.x * blockDim.x + tid) >> 5;  // batch index
  if (g < B) {
    float th = theta[g], ph = phi[g];
    float cth, sth; sincosf(0.5f * th, &sth, &cth);
    float cph, sph; sincosf(0.5f * ph, &sph, &cph);

    // ---- fused all-wire RZ(phi) phases via complex mult of (cph,sph):
    // wz[j] = e^{i*phi*(popc(L) + j - 4)}, j = popc(r) in [0,3].
    v2f wz[4];
    {
      float z2r = cph*cph - sph*sph,  z2i = 2.f*cph*sph;   // e^{i phi}
      float z4r = z2r*z2r - z2i*z2i,  z4i = 2.f*z2r*z2i;   // e^{2i phi}
      float z8r = z4r*z4r - z4i*z4i,  z8i = 2.f*z4r*z4i;   // e^{4i phi}
      int e = __popc(L) - 4;            // [-4, 1]
      int q = e < 0 ? -e : e;           // 0..4
      float t1r = (q & 1) ? z2r : 1.f, t1i = (q & 1) ? z2i : 0.f;
      float t2r = (q & 2) ? z4r : 1.f, t2i = (q & 2) ? z4i : 0.f;
      float t3r = (q & 4) ? z8r : 1.f, t3i = (q & 4) ? z8i : 0.f;
      float pr = t1r*t2r - t1i*t2i,    pi = t1r*t2i + t1i*t2r;
      float br = pr*t3r - pi*t3i,      bi = pr*t3i + pi*t3r;
      bi = (e < 0) ? -bi : bi;
      wz[0] = (v2f){br, bi};
      wz[1] = (v2f){wz[0].x*z2r - wz[0].y*z2i, wz[0].x*z2i + wz[0].y*z2r};
      wz[2] = (v2f){wz[1].x*z2r - wz[1].y*z2i, wz[1].x*z2i + wz[1].y*z2r};
      wz[3] = (v2f){wz[2].x*z2r - wz[2].y*z2i, wz[2].x*z2i + wz[2].y*z2r};
    }

    State st;
    // ---- cycle 1 RY layer closed-form: amp(a) = c^#zeros * s^#ones ----
    {
      float F = (L & 1)  ? sth : cth;
      F *=      (L & 2)  ? sth : cth;
      F *=      (L & 4)  ? sth : cth;
      F *=      (L & 8)  ? sth : cth;
      F *=      (L & 16) ? sth : cth;
      #pragma unroll
      for (int r = 0; r < NREG; ++r) {
        float X = ((r & 1) ? sth : cth) * ((r & 2) ? sth : cth) * ((r & 4) ? sth : cth);
        st.a[r] = (v2f){F * X, 0.f};
      }
    }
    // cycle 1: fused RZ diagonal + CNOT ring
    #pragma unroll
    for (int r = 0; r < NREG; ++r) {
      v2f w = wz[__builtin_popcount(r)];
      v2f v = st.a[r];
      st.a[r] = vfma((v2f){-w.y, w.y}, v.yx, splat(w.x) * v);
    }
    cnot_cascade(st, bp_addr);
    cnot_gate<3,2>(st, L);
    cnot_gate<2,1>(st, L);
    cnot_gate<1,0>(st, L);
    cnot_gate<0,7>(st, L);

    // cycles 2..4
    #pragma unroll 1
    for (int cyc = 0; cyc < 3; ++cyc) {
      ry_gate<7>(st, cth, sth, L);
      ry_gate<6>(st, cth, sth, L);
      ry_gate<5>(st, cth, sth, L);
      ry_gate<4>(st, cth, sth, L);
      ry_gate<3>(st, cth, sth, L);
      ry_gate<2>(st, cth, sth, L);
      ry_gate<1>(st, cth, sth, L);
      ry_gate<0>(st, cth, sth, L);
      #pragma unroll
      for (int r = 0; r < NREG; ++r) {
        v2f w = wz[__builtin_popcount(r)];
        v2f v = st.a[r];
        st.a[r] = vfma((v2f){-w.y, w.y}, v.yx, splat(w.x) * v);
      }
      cnot_cascade(st, bp_addr);
      cnot_gate<3,2>(st, L);
      cnot_gate<2,1>(st, L);
      cnot_gate<1,0>(st, L);
      cnot_gate<0,7>(st, L);
    }

    // fused post-cycle (validated R15/R16)
    apply_G_ll<8, 16>(st, sG + 0 * 32, L);  // (1,0) -> bits (6,7)
    apply_G_ll<2, 4>(st, sG + 1 * 32, L);   // (3,2) -> bits (4,5)
    apply_G_mx<4, 1>(st, sG + 2 * 32, L);   // (5,4) -> bits (2,3)
    apply_G_rr<1, 2>(st, sG + 3 * 32);      // (7,6) -> bits (0,1)
    apply_G_ll<2, 8>(st, sG + 4 * 32, L);   // (3,1) -> bits (4,6)
    apply_G_rr<1, 4>(st, sG + 5 * 32);      // (7,5) -> bits (0,2)
    apply_G_mx<4, 2>(st, sG + 6 * 32, L);   // (5,3) -> bits (2,4)

    // expval_z on wire 3 (lane bit 1) and wire 7 (reg bit 0)
    float s3 = 0.f, s7 = 0.f;
    #pragma unroll
    for (int r = 0; r < NREG; ++r) {
      v2f sq = st.a[r] * st.a[r];
      float p = sq.x + sq.y;
      s3 += p;
      s7 += (r & 1) ? -p : p;
    }
    if ((L >> 1) & 1) s3 = -s3;
    s3 += lxor<1>(s3);  s7 += lxor<1>(s7);
    s3 += lxor<2>(s3);  s7 += lxor<2>(s7);
    s3 += lxor<4>(s3);  s7 += lxor<4>(s7);
    s3 += lxor<8>(s3);  s7 += lxor<8>(s7);
    s3 += lxor<16>(s3); s7 += lxor<16>(s7);

    // MLP head
    float y = s_b2[0];
    #pragma unroll
    for (int j = 0; j < 10; ++j) {
      float h = tanhf(fmaf(s3, s_w1[2*j], fmaf(s7, s_w1[2*j+1], s_b1[j])));
      y = fmaf(h, s_w2[j], y);
    }
    float res = 1.f / (1.f + expf(-y));
    if (L == 0) out[g] = res;
  }
}

extern "C" void kernel_launch(void* const* d_in, const int* in_sizes, int n_in,
                              void* d_out, int out_size, void* d_ws, size_t ws_size,
                              hipStream_t stream) {
  const float* theta = (const float*)d_in[0];
  const float* phi   = (const float*)d_in[1];
  const float* rz_a  = (const float*)d_in[2];
  const float* ry_a  = (const float*)d_in[3];
  const float* u3_p  = (const float*)d_in[4];
  const float* w1    = (const float*)d_in[5];
  const float* b1    = (const float*)d_in[6];
  const float* w2    = (const float*)d_in[7];
  const float* b2    = (const float*)d_in[8];
  float* out = (float*)d_out;
  float* ws  = (float*)d_ws;
  const int B = in_sizes[0];

  hipLaunchKernelGGL(build_gates_kernel, dim3(1), dim3(64), 0, stream,
                     rz_a, ry_a, u3_p, ws);

  const int threads = 256;
  const int blocks = (B * 32 + threads - 1) / threads;
  hipLaunchKernelGGL(qcnn_kernel, dim3(blocks), dim3(threads), 0, stream,
                     theta, phi, ws, w1, b1, w2, b2, out, B);
}

// Round 20
// 25.791 us; speedup vs baseline: 1.0969x; 1.0969x over previous
//
#include <hip/hip_runtime.h>
#include <math.h>

// Batched 8-qubit state-vector sim. fp32 in / fp32 out.
// Base: R18 (PASSED, 26.0us). R19's DS->VALU offload regressed AGAIN (2nd
// trial) - ds_swizzle mix is optimal; family buried.
// This round: fold ring CNOT (0,7) into the cascade bpermute. Ring =
// casc*A<3,2>*B<2,1>*C<1,0>*D<0,7>; conjugating D leftward gives D''' =
// flip lane-bit4 iff parity(reg bits 0..2) XOR lane-bit0, applied right after
// casc and composed into its pull: addr = S(y ^ 16*(p_r ^ (y&1))). One
// bpermute per value, two precomputed addresses selected by reg parity.
// NOTE: popcount-fused RZ via sincosf-into-indexed-arrays is FORBIDDEN
// (R1/R9); the complex-mult phase build (R18) is the validated form.
// Layout: one element per 32-lane group; a = L*8 + r; wire w -> bit 7-w;
// bit<3 = reg bit (mask 1<<bit), bit>=3 = lane bit (mask 1<<(bit-3)).

constexpr int NREG = 8;

typedef float v2f __attribute__((ext_vector_type(2)));

__device__ __forceinline__ v2f vfma(v2f a, v2f b, v2f c) {
  return __builtin_elementwise_fma(a, b, c);
}
__device__ __forceinline__ v2f splat(float x) { return (v2f){x, x}; }

template<int MASK>
__device__ __forceinline__ float lxor(float x) {
  int xi = __float_as_int(x);
  int r;
  if constexpr (MASK == 1)      r = __builtin_amdgcn_mov_dpp(xi, 0xB1, 0xF, 0xF, true); // quad_perm [1,0,3,2]
  else if constexpr (MASK == 2) r = __builtin_amdgcn_mov_dpp(xi, 0x4E, 0xF, 0xF, true); // quad_perm [2,3,0,1]
  else                          r = __builtin_amdgcn_ds_swizzle(xi, (MASK << 10) | 0x1F); // xor within 32 lanes
  return __int_as_float(r);
}

template<int MASK>
__device__ __forceinline__ v2f lxor2(v2f v) {
  v2f r;
  r.x = lxor<MASK>(v.x);
  r.y = lxor<MASK>(v.y);
  return r;
}

struct State {
  v2f a[NREG];  // a[r] = (re, im)
};

// ---------------- cycle-layer gates (validated R12/R17) ----------------

template<int P>
__device__ __forceinline__ void ry_gate(State& st, float c, float s, int L) {
  if constexpr (P <= 2) {
    constexpr int m = 1 << P;
    #pragma unroll
    for (int r0 = 0; r0 < NREG; ++r0) {
      if (r0 & m) continue;
      const int r1 = r0 | m;
      v2f a0 = st.a[r0], a1 = st.a[r1];
      st.a[r0] = vfma(splat(-s), a1, splat(c) * a0);
      st.a[r1] = vfma(splat( s), a0, splat(c) * a1);
    }
  } else {
    constexpr int m = 1 << (P - 3);
    float ss = ((L >> (P - 3)) & 1) ? s : -s;
    #pragma unroll
    for (int r = 0; r < NREG; ++r) {
      v2f b = lxor2<m>(st.a[r]);
      st.a[r] = vfma(splat(ss), b, splat(c) * st.a[r]);
    }
  }
}

template<int PC, int PT>
__device__ __forceinline__ void cnot_gate(State& st, int L) {
  if constexpr (PT <= 2) {
    constexpr int mt = 1 << PT;
    if constexpr (PC <= 2) {
      constexpr int mc = 1 << PC;
      #pragma unroll
      for (int r0 = 0; r0 < NREG; ++r0) {
        if (!(r0 & mc) || (r0 & mt)) continue;
        const int r1 = r0 | mt;
        v2f t = st.a[r0]; st.a[r0] = st.a[r1]; st.a[r1] = t;
      }
    } else {
      bool cb = (L >> (PC - 3)) & 1;
      #pragma unroll
      for (int r0 = 0; r0 < NREG; ++r0) {
        if (r0 & mt) continue;
        const int r1 = r0 | mt;
        v2f a0 = st.a[r0], a1 = st.a[r1];
        st.a[r0] = cb ? a1 : a0;
        st.a[r1] = cb ? a0 : a1;
      }
    }
  } else {
    constexpr int mt = 1 << (PT - 3);
    if constexpr (PC <= 2) {
      constexpr int mc = 1 << PC;
      #pragma unroll
      for (int r = 0; r < NREG; ++r) {
        if (!(r & mc)) continue;
        st.a[r] = lxor2<mt>(st.a[r]);
      }
    } else {
      bool cb = (L >> (PC - 3)) & 1;
      #pragma unroll
      for (int r = 0; r < NREG; ++r) {
        v2f b = lxor2<mt>(st.a[r]);
        st.a[r] = cb ? b : st.a[r];
      }
    }
  }
}

// casc (ring CNOTs on lane bits) composed with D''' (folded cnot<0,7>):
// per reg r, pull addr = a_odd if popc(r) odd else a_even.
__device__ __forceinline__ void cnot_cascade_d(State& st, int a_even, int a_odd) {
  #pragma unroll
  for (int r = 0; r < NREG; ++r) {
    const int addr = (__builtin_popcount(r) & 1) ? a_odd : a_even;
    int xr = __builtin_amdgcn_ds_bpermute(addr, __float_as_int(st.a[r].x));
    int xi = __builtin_amdgcn_ds_bpermute(addr, __float_as_int(st.a[r].y));
    st.a[r].x = __int_as_float(xr);
    st.a[r].y = __int_as_float(xi);
  }
}

// t += (ur + i*ui) * v
__device__ __forceinline__ v2f cmac(v2f t, v2f u, v2f v) {
  t = vfma(splat(u.x), v, t);
  t = vfma((v2f){-u.y, u.y}, v.yx, t);
  return t;
}

__device__ __forceinline__ v2f ld2(const float* p) {
  return (v2f){p[0], p[1]};
}

// ---------------- fused 4x4 gate application (validated R15/R16) ------------

template<int MH, int ML>
__device__ __forceinline__ void apply_G_ll(State& st, const float* g, int L) {
  const int bh = (L & MH) ? 1 : 0;
  const int bl = (L & ML) ? 1 : 0;
  const int row = (bh << 1) | bl;
  const float* gr = g + row * 8;
  const v2f cS = ld2(gr + 2 * row);
  const v2f cL = ld2(gr + 2 * (row ^ 1));
  const v2f cH = ld2(gr + 2 * (row ^ 2));
  const v2f cB = ld2(gr + 2 * (row ^ 3));
  #pragma unroll
  for (int r = 0; r < NREG; ++r) {
    v2f v = st.a[r];
    v2f pl = lxor2<ML>(v);
    v2f ph = lxor2<MH>(v);
    v2f pb = lxor2<MH | ML>(v);
    v2f t = (v2f){0.f, 0.f};
    t = cmac(t, cS, v);
    t = cmac(t, cL, pl);
    t = cmac(t, cH, ph);
    t = cmac(t, cB, pb);
    st.a[r] = t;
  }
}

template<int MHR, int MLR>
__device__ __forceinline__ void apply_G_rr(State& st, const float* g) {
  #pragma unroll
  for (int base = 0; base < NREG; ++base) {
    if (base & (MHR | MLR)) continue;
    v2f in0 = st.a[base];
    v2f in1 = st.a[base | MLR];
    v2f in2 = st.a[base | MHR];
    v2f in3 = st.a[base | MHR | MLR];
    #pragma unroll
    for (int i = 0; i < 4; ++i) {
      v2f t = (v2f){0.f, 0.f};
      t = cmac(t, ld2(g + i * 8 + 0), in0);
      t = cmac(t, ld2(g + i * 8 + 2), in1);
      t = cmac(t, ld2(g + i * 8 + 4), in2);
      t = cmac(t, ld2(g + i * 8 + 6), in3);
      if (i == 0) st.a[base] = t;
      else if (i == 1) st.a[base | MLR] = t;
      else if (i == 2) st.a[base | MHR] = t;
      else st.a[base | MHR | MLR] = t;
    }
  }
}

template<int MREG, int ML>
__device__ __forceinline__ void apply_G_mx(State& st, const float* g, int L) {
  const int bl = (L & ML) ? 1 : 0;
  const int r0w = bl;
  const int r1w = 2 + bl;
  const float* g0 = g + r0w * 8;
  const float* g1 = g + r1w * 8;
  const v2f c0S = ld2(g0 + 2 * r0w),       c0L = ld2(g0 + 2 * (r0w ^ 1));
  const v2f c0H = ld2(g0 + 2 * (r0w ^ 2)), c0B = ld2(g0 + 2 * (r0w ^ 3));
  const v2f c1S = ld2(g1 + 2 * r1w),       c1L = ld2(g1 + 2 * (r1w ^ 1));
  const v2f c1H = ld2(g1 + 2 * (r1w ^ 2)), c1B = ld2(g1 + 2 * (r1w ^ 3));
  v2f x[NREG];
  #pragma unroll
  for (int r = 0; r < NREG; ++r) x[r] = lxor2<ML>(st.a[r]);
  v2f o[NREG];
  #pragma unroll
  for (int r = 0; r < NREG; ++r) {
    v2f t = (v2f){0.f, 0.f};
    if (r & MREG) {
      t = cmac(t, c1S, st.a[r]);
      t = cmac(t, c1L, x[r]);
      t = cmac(t, c1H, st.a[r ^ MREG]);
      t = cmac(t, c1B, x[r ^ MREG]);
    } else {
      t = cmac(t, c0S, st.a[r]);
      t = cmac(t, c0L, x[r]);
      t = cmac(t, c0H, st.a[r ^ MREG]);
      t = cmac(t, c0B, x[r ^ MREG]);
    }
    o[r] = t;
  }
  #pragma unroll
  for (int r = 0; r < NREG; ++r) st.a[r] = o[r];
}

// ---------------- gate-build helpers (4-dim basis column) ----------------

__device__ __forceinline__ void b_phase(float* cr, float* ci, int i, float pc, float ps) {
  float r = cr[i] * pc - ci[i] * ps;
  float m = cr[i] * ps + ci[i] * pc;
  cr[i] = r; ci[i] = m;
}
__device__ __forceinline__ void b_rz_hi(float* cr, float* ci, float t) {
  float s, c; sincosf(0.5f * t, &s, &c);
  b_phase(cr, ci, 0, c, -s); b_phase(cr, ci, 1, c, -s);
  b_phase(cr, ci, 2, c,  s); b_phase(cr, ci, 3, c,  s);
}
__device__ __forceinline__ void b_rz_lo(float* cr, float* ci, float t) {
  float s, c; sincosf(0.5f * t, &s, &c);
  b_phase(cr, ci, 0, c, -s); b_phase(cr, ci, 2, c, -s);
  b_phase(cr, ci, 1, c,  s); b_phase(cr, ci, 3, c,  s);
}
__device__ __forceinline__ void b_ry_hi(float* cr, float* ci, float t) {
  float s, c; sincosf(0.5f * t, &s, &c);
  #pragma unroll
  for (int lo = 0; lo < 2; ++lo) {
    int i0 = lo, i1 = 2 + lo;
    float n0r = c * cr[i0] - s * cr[i1], n0i = c * ci[i0] - s * ci[i1];
    float n1r = s * cr[i0] + c * cr[i1], n1i = s * ci[i0] + c * ci[i1];
    cr[i0] = n0r; ci[i0] = n0i; cr[i1] = n1r; ci[i1] = n1i;
  }
}
__device__ __forceinline__ void b_swap(float* cr, float* ci, int i, int j) {
  float t;
  t = cr[i]; cr[i] = cr[j]; cr[j] = t;
  t = ci[i]; ci[i] = ci[j]; ci[j] = t;
}
__device__ __forceinline__ void b_u2(float* cr, float* ci, int i0, int i1,
    float u00r, float u00i, float u01r, float u01i,
    float u10r, float u10i, float u11r, float u11i) {
  float v0r = cr[i0], v0i = ci[i0], v1r = cr[i1], v1i = ci[i1];
  cr[i0] = u00r*v0r - u00i*v0i + u01r*v1r - u01i*v1i;
  ci[i0] = u00r*v0i + u00i*v0r + u01r*v1i + u01i*v1r;
  cr[i1] = u10r*v0r - u10i*v0i + u11r*v1r - u11i*v1i;
  ci[i1] = u10r*v0i + u10i*v0r + u11r*v1i + u11i*v1r;
}
__device__ __forceinline__ void b_u3(float* cr, float* ci, bool on_hi,
                                     float t, float p, float l) {
  float st_, ct, sp, cp, sl, cl;
  sincosf(0.5f * t, &st_, &ct);
  sincosf(p, &sp, &cp);
  sincosf(l, &sl, &cl);
  float u00r = ct,        u00i = 0.f;
  float u01r = -cl * st_, u01i = -sl * st_;
  float u10r = cp * st_,  u10i = sp * st_;
  float eplr = cp * cl - sp * sl, epli = sp * cl + cp * sl;
  float u11r = eplr * ct, u11i = epli * ct;
  if (on_hi) {
    b_u2(cr, ci, 0, 2, u00r,u00i,u01r,u01i,u10r,u10i,u11r,u11i);
    b_u2(cr, ci, 1, 3, u00r,u00i,u01r,u01i,u10r,u10i,u11r,u11i);
  } else {
    b_u2(cr, ci, 0, 1, u00r,u00i,u01r,u01i,u10r,u10i,u11r,u11i);
    b_u2(cr, ci, 2, 3, u00r,u00i,u01r,u01i,u10r,u10i,u11r,u11i);
  }
}

// ---------------- kernel 1: build 7 fused 4x4 gates into d_ws --------------

__global__ __launch_bounds__(64, 1) void build_gates_kernel(
    const float* __restrict__ rz_a, const float* __restrict__ ry_a,
    const float* __restrict__ u3_p, float* __restrict__ ws) {
  const int tid = threadIdx.x;
  if (tid >= 28) return;
  const int t = tid >> 2;
  const int j = tid & 3;
  float cr[4] = {0.f, 0.f, 0.f, 0.f};
  float ci[4] = {0.f, 0.f, 0.f, 0.f};
  cr[j] = 1.f;
  b_rz_hi(cr, ci, rz_a[3 * t]);
  b_swap(cr, ci, 2, 3);                 // cnot(hi,lo)
  b_rz_lo(cr, ci, rz_a[3 * t + 1]);
  b_ry_hi(cr, ci, ry_a[2 * t]);
  b_swap(cr, ci, 1, 3);                 // cnot(lo,hi)
  b_ry_hi(cr, ci, ry_a[2 * t + 1]);
  b_swap(cr, ci, 2, 3);                 // cnot(hi,lo)
  b_rz_lo(cr, ci, rz_a[3 * t + 2]);
  if (t < 4)       b_u3(cr, ci, true,  u3_p[3*t], u3_p[3*t+1], u3_p[3*t+2]);
  else if (t == 5) b_u3(cr, ci, true,  u3_p[15],  u3_p[16],    u3_p[17]);
  else if (t == 6) b_u3(cr, ci, false, u3_p[12],  u3_p[13],    u3_p[14]);
  #pragma unroll
  for (int i = 0; i < 4; ++i) {
    ws[t * 32 + i * 8 + j * 2]     = cr[i];
    ws[t * 32 + i * 8 + j * 2 + 1] = ci[i];
  }
}

// ---------------- kernel 2: main ----------------

__global__ __launch_bounds__(256, 4) void qcnn_kernel(
    const float* __restrict__ theta, const float* __restrict__ phi,
    const float* __restrict__ ws,
    const float* __restrict__ w1, const float* __restrict__ b1,
    const float* __restrict__ w2, const float* __restrict__ b2,
    float* __restrict__ out, int B) {
  __shared__ float sG[7 * 32] __attribute__((aligned(16)));
  __shared__ float s_w1[20];
  __shared__ float s_b1[10];
  __shared__ float s_w2[10];
  __shared__ float s_b2[1];

  const int tid = threadIdx.x;
  if (tid < 224) sG[tid] = ws[tid];
  if (tid < 20) s_w1[tid] = w1[tid];
  else if (tid >= 32 && tid < 42) s_b1[tid - 32] = b1[tid - 32];
  else if (tid >= 64 && tid < 74) s_w2[tid - 64] = w2[tid - 64];
  else if (tid == 96) s_b2[0] = b2[0];
  __syncthreads();

  const int L = tid & 31;
  const int wv = tid & 63;
  // cascade+D''' pull addrs: S(u) = u ^ ((u>>1)&15); cond = p_r ^ (L&1)
  const int hi32 = wv & 32;
  const int c0 = (L & 1) ? 16 : 0;
  const int ue = L ^ c0;          // partner pre-lane for even-parity regs
  const int uo = L ^ c0 ^ 16;     // for odd-parity regs
  const int a_even = (hi32 | (ue ^ ((ue >> 1) & 15))) << 2;
  const int a_odd  = (hi32 | (uo ^ ((uo >> 1) & 15))) << 2;
  const int g = (blockIdx.x * blockDim.x + tid) >> 5;  // batch index
  if (g < B) {
    float th = theta[g], ph = phi[g];
    float cth, sth; sincosf(0.5f * th, &sth, &cth);
    float cph, sph; sincosf(0.5f * ph, &sph, &cph);

    // ---- fused all-wire RZ(phi) phases via complex mult of (cph,sph):
    // wz[j] = e^{i*phi*(popc(L) + j - 4)}, j = popc(r) in [0,3].
    v2f wz[4];
    {
      float z2r = cph*cph - sph*sph,  z2i = 2.f*cph*sph;   // e^{i phi}
      float z4r = z2r*z2r - z2i*z2i,  z4i = 2.f*z2r*z2i;   // e^{2i phi}
      float z8r = z4r*z4r - z4i*z4i,  z8i = 2.f*z4r*z4i;   // e^{4i phi}
      int e = __popc(L) - 4;            // [-4, 1]
      int q = e < 0 ? -e : e;           // 0..4
      float t1r = (q & 1) ? z2r : 1.f, t1i = (q & 1) ? z2i : 0.f;
      float t2r = (q & 2) ? z4r : 1.f, t2i = (q & 2) ? z4i : 0.f;
      float t3r = (q & 4) ? z8r : 1.f, t3i = (q & 4) ? z8i : 0.f;
      float pr = t1r*t2r - t1i*t2i,    pi = t1r*t2i + t1i*t2r;
      float br = pr*t3r - pi*t3i,      bi = pr*t3i + pi*t3r;
      bi = (e < 0) ? -bi : bi;
      wz[0] = (v2f){br, bi};
      wz[1] = (v2f){wz[0].x*z2r - wz[0].y*z2i, wz[0].x*z2i + wz[0].y*z2r};
      wz[2] = (v2f){wz[1].x*z2r - wz[1].y*z2i, wz[1].x*z2i + wz[1].y*z2r};
      wz[3] = (v2f){wz[2].x*z2r - wz[2].y*z2i, wz[2].x*z2i + wz[2].y*z2r};
    }

    State st;
    // ---- cycle 1 RY layer closed-form: amp(a) = c^#zeros * s^#ones ----
    {
      float F = (L & 1)  ? sth : cth;
      F *=      (L & 2)  ? sth : cth;
      F *=      (L & 4)  ? sth : cth;
      F *=      (L & 8)  ? sth : cth;
      F *=      (L & 16) ? sth : cth;
      #pragma unroll
      for (int r = 0; r < NREG; ++r) {
        float X = ((r & 1) ? sth : cth) * ((r & 2) ? sth : cth) * ((r & 4) ? sth : cth);
        st.a[r] = (v2f){F * X, 0.f};
      }
    }
    // cycle 1: fused RZ diagonal + CNOT ring (casc+D''' then reg cnots)
    #pragma unroll
    for (int r = 0; r < NREG; ++r) {
      v2f w = wz[__builtin_popcount(r)];
      v2f v = st.a[r];
      st.a[r] = vfma((v2f){-w.y, w.y}, v.yx, splat(w.x) * v);
    }
    cnot_cascade_d(st, a_even, a_odd);
    cnot_gate<3,2>(st, L);
    cnot_gate<2,1>(st, L);
    cnot_gate<1,0>(st, L);

    // cycles 2..4
    #pragma unroll 1
    for (int cyc = 0; cyc < 3; ++cyc) {
      ry_gate<7>(st, cth, sth, L);
      ry_gate<6>(st, cth, sth, L);
      ry_gate<5>(st, cth, sth, L);
      ry_gate<4>(st, cth, sth, L);
      ry_gate<3>(st, cth, sth, L);
      ry_gate<2>(st, cth, sth, L);
      ry_gate<1>(st, cth, sth, L);
      ry_gate<0>(st, cth, sth, L);
      #pragma unroll
      for (int r = 0; r < NREG; ++r) {
        v2f w = wz[__builtin_popcount(r)];
        v2f v = st.a[r];
        st.a[r] = vfma((v2f){-w.y, w.y}, v.yx, splat(w.x) * v);
      }
      cnot_cascade_d(st, a_even, a_odd);
      cnot_gate<3,2>(st, L);
      cnot_gate<2,1>(st, L);
      cnot_gate<1,0>(st, L);
    }

    // fused post-cycle (validated R15/R16)
    apply_G_ll<8, 16>(st, sG + 0 * 32, L);  // (1,0) -> bits (6,7)
    apply_G_ll<2, 4>(st, sG + 1 * 32, L);   // (3,2) -> bits (4,5)
    apply_G_mx<4, 1>(st, sG + 2 * 32, L);   // (5,4) -> bits (2,3)
    apply_G_rr<1, 2>(st, sG + 3 * 32);      // (7,6) -> bits (0,1)
    apply_G_ll<2, 8>(st, sG + 4 * 32, L);   // (3,1) -> bits (4,6)
    apply_G_rr<1, 4>(st, sG + 5 * 32);      // (7,5) -> bits (0,2)
    apply_G_mx<4, 2>(st, sG + 6 * 32, L);   // (5,3) -> bits (2,4)

    // expval_z on wire 3 (lane bit 1) and wire 7 (reg bit 0)
    float s3 = 0.f, s7 = 0.f;
    #pragma unroll
    for (int r = 0; r < NREG; ++r) {
      v2f sq = st.a[r] * st.a[r];
      float p = sq.x + sq.y;
      s3 += p;
      s7 += (r & 1) ? -p : p;
    }
    if ((L >> 1) & 1) s3 = -s3;
    s3 += lxor<1>(s3);  s7 += lxor<1>(s7);
    s3 += lxor<2>(s3);  s7 += lxor<2>(s7);
    s3 += lxor<4>(s3);  s7 += lxor<4>(s7);
    s3 += lxor<8>(s3);  s7 += lxor<8>(s7);
    s3 += lxor<16>(s3); s7 += lxor<16>(s7);

    // MLP head
    float y = s_b2[0];
    #pragma unroll
    for (int j = 0; j < 10; ++j) {
      float h = tanhf(fmaf(s3, s_w1[2*j], fmaf(s7, s_w1[2*j+1], s_b1[j])));
      y = fmaf(h, s_w2[j], y);
    }
    float res = 1.f / (1.f + expf(-y));
    if (L == 0) out[g] = res;
  }
}

extern "C" void kernel_launch(void* const* d_in, const int* in_sizes, int n_in,
                              void* d_out, int out_size, void* d_ws, size_t ws_size,
                              hipStream_t stream) {
  const float* theta = (const float*)d_in[0];
  const float* phi   = (const float*)d_in[1];
  const float* rz_a  = (const float*)d_in[2];
  const float* ry_a  = (const float*)d_in[3];
  const float* u3_p  = (const float*)d_in[4];
  const float* w1    = (const float*)d_in[5];
  const float* b1    = (const float*)d_in[6];
  const float* w2    = (const float*)d_in[7];
  const float* b2    = (const float*)d_in[8];
  float* out = (float*)d_out;
  float* ws  = (float*)d_ws;
  const int B = in_sizes[0];

  hipLaunchKernelGGL(build_gates_kernel, dim3(1), dim3(64), 0, stream,
                     rz_a, ry_a, u3_p, ws);

  const int threads = 256;
  const int blocks = (B * 32 + threads - 1) / threads;
  hipLaunchKernelGGL(qcnn_kernel, dim3(blocks), dim3(threads), 0, stream,
                     theta, phi, ws, w1, b1, w2, b2, out, B);
}